// Round 1
// 319.364 us; speedup vs baseline: 1.0141x; 1.0141x over previous
//
#include <hip/hip_runtime.h>
#include <math.h>

// Problem constants (fixed by setup_inputs)
#define B   32
#define C   192
#define CS  48      // C / N_SPLIT
#define T   8192
#define TV  2048    // T / 4   (float4 elements along t)
#define TVQ 512     // TV / 4  (each thread does 4 t-positions, stride TVQ)
#define ZBLOCKS ((B * CS * TVQ) / 256)   // 3072 streaming blocks

typedef float f4 __attribute__((ext_vector_type(4)));

// Fused kernel:
//   blocks [0, ZBLOCKS)          : z = shuffle+4x4 mix of x, masked (streaming)
//   blocks [ZBLOCKS, ZBLOCKS+B)  : logdet[b] (tiny reduction, hides under stream)
//
// z[b, c, t]: for each (b, j, t), channels {2j, 2j+1, 96+2j, 96+2j+1}
// (split index n = 2g + k for c = 96g + 2j + k) mixed by 4x4 W, times mask.
// x / z are nontemporal zero-reuse streams; mask stays cached.
__global__ __launch_bounds__(256) void invconv_fused(
    const f4* __restrict__ x, const f4* __restrict__ mask,
    const float* __restrict__ w, f4* __restrict__ out,
    float* __restrict__ ld)
{
    if (blockIdx.x >= ZBLOCKS) {
        // ---- logdet path: one block per batch, dispatched last ----
        int b = blockIdx.x - ZBLOCKS;
        const f4* mp = mask + (long)b * TV;
        float s = 0.f;
#pragma unroll
        for (int q = 0; q < 8; ++q) {          // 256 thr x 8 f4 = 2048 f4
            f4 v = mp[threadIdx.x + q * 256];
            s += (v.x + v.y) + (v.z + v.w);
        }
#pragma unroll
        for (int off = 32; off; off >>= 1) s += __shfl_down(s, off, 64);

        __shared__ float partial[4];
        int lane = threadIdx.x & 63, wv = threadIdx.x >> 6;
        if (lane == 0) partial[wv] = s;
        __syncthreads();

        if (threadIdx.x == 0) {
            float xlen = (partial[0] + partial[1]) + (partial[2] + partial[3]);
            double a[16];
#pragma unroll
            for (int i = 0; i < 16; ++i) a[i] = (double)w[i];
            // det(4x4) via 2x2-block cofactors in double: W ~ orthogonal so
            // log|det| ~ 0 and gets amplified by 48*8192 -> need precision.
            double s0 = a[0]*a[5]  - a[1]*a[4];
            double s1 = a[0]*a[6]  - a[2]*a[4];
            double s2 = a[0]*a[7]  - a[3]*a[4];
            double s3 = a[1]*a[6]  - a[2]*a[5];
            double s4 = a[1]*a[7]  - a[3]*a[5];
            double s5 = a[2]*a[7]  - a[3]*a[6];
            double c5 = a[10]*a[15] - a[11]*a[14];
            double c4 = a[9]*a[15]  - a[11]*a[13];
            double c3 = a[9]*a[14]  - a[10]*a[13];
            double c2 = a[8]*a[15]  - a[11]*a[12];
            double c1 = a[8]*a[14]  - a[10]*a[12];
            double c0 = a[8]*a[13]  - a[9]*a[12];
            double det = s0*c5 - s1*c4 + s2*c3 + s3*c2 - s4*c1 + s5*c0;
            ld[b] = (float)(log(fabs(det)) * (double)(C / 4) * (double)xlen);
        }
        return;
    }

    // ---- streaming z path (unchanged) ----
    int gid = blockIdx.x * 256 + threadIdx.x;   // [0, B*CS*TVQ)
    int tv  = gid & (TVQ - 1);
    int bj  = gid >> 9;                         // / TVQ
    int j   = bj % CS;
    int b   = bj / CS;

    // Thread-invariant weight -> scalar loads (broadcast)
    float wr[16];
#pragma unroll
    for (int i = 0; i < 16; ++i) wr[i] = w[i];

    long base = (long)b * C * TV;
    int  c0   = 2 * j;         // split 0/1 pair
    int  c2   = 96 + 2 * j;    // split 2/3 pair
    int  cio[4] = { c0, c0 + 1, c2, c2 + 1 };

    // 16 nontemporal loads in flight (4 t-positions x 4 channels)
    f4 a[4][4];                 // [tpos][chan]
    const f4* p[4];
#pragma unroll
    for (int n = 0; n < 4; ++n) {
        p[n] = x + base + (long)cio[n] * TV + tv;
#pragma unroll
        for (int q = 0; q < 4; ++q)
            a[q][n] = __builtin_nontemporal_load(p[n] + q * TVQ);
    }
    const f4* mp = mask + (long)b * TV + tv;
    f4 m[4];
#pragma unroll
    for (int q = 0; q < 4; ++q) m[q] = mp[q * TVQ];

#pragma unroll
    for (int i = 0; i < 4; ++i) {
        f4* d = out + (p[i] - x);   // same offset as input channel cio[i]
#pragma unroll
        for (int q = 0; q < 4; ++q) {
            f4 o = (f4)(0.f);
#pragma unroll
            for (int n = 0; n < 4; ++n) o += wr[i * 4 + n] * a[q][n];
            o *= m[q];
            __builtin_nontemporal_store(o, d + q * TVQ);
        }
    }
}

extern "C" void kernel_launch(void* const* d_in, const int* in_sizes, int n_in,
                              void* d_out, int out_size, void* d_ws, size_t ws_size,
                              hipStream_t stream) {
    const float* x    = (const float*)d_in[0];   // (32, 192, 8192) fp32
    const float* mask = (const float*)d_in[1];   // (32, 1, 8192) fp32
    const float* w    = (const float*)d_in[2];   // (4, 4) fp32
    float* z  = (float*)d_out;                           // 32*192*8192
    float* ld = (float*)d_out + (size_t)B * C * T;       // +32

    invconv_fused<<<ZBLOCKS + B, 256, 0, stream>>>(
        (const f4*)x, (const f4*)mask, w, (f4*)z, ld);
}